// Round 6
// baseline (173.736 us; speedup 1.0000x reference)
//
#include <hip/hip_runtime.h>

#define NB    32
#define CIN   64
#define COUT  128
#define HH    56
#define WW    56
#define NPIX  (NB*HH*WW)
#define BN_EPSF 1e-5f

typedef __bf16 bf16x8 __attribute__((ext_vector_type(8)));
typedef float  f32x4  __attribute__((ext_vector_type(4)));

// ---------------- zero the stats accumulators --------------------------------
__global__ void zero_sums(float* g) {
    g[threadIdx.x] = 0.0f;        // 256 floats: gsum[128] + gsq[128]
}

// ------- assemble block-diag weights -> bf16, [tap][half][oc][32] ------------
__global__ void assemble_w(const float* __restrict__ wb, __bf16* __restrict__ whi) {
    int idx = blockIdx.x * 256 + threadIdx.x;
    if (idx >= 576 * 128) return;
    int col = idx >> 7, oc = idx & 127;          // col = ic*9 + kh*3 + kw
    int p = oc >> 3, i = oc & 7, q = col >> 3, j = col & 7;
    float v = wb[((p * 72 + q) * 8 + i) * 8 + j];
    int ic = col / 9, tap = col % 9;
    int dst = ((tap * 2 + (ic >> 5)) * 128 + oc) * 32 + (ic & 31);
    whi[dst] = (__bf16)v;
}

// ---------------- MFMA implicit-GEMM conv, barrier-free K-loop ---------------
// block: image n, 8x8 spatial tile (M=64), all 128 oc. 4 waves x 32 oc.
// x halo staged once in LDS (bf16, XOR-swizzled 16B chunks);
// B-fragments read directly from global (L2-resident, 144 KB total).
__global__ __launch_bounds__(256, 8) void conv_mfma(
    const float* __restrict__ x, const __bf16* __restrict__ whi,
    float* __restrict__ y, float* __restrict__ gsum, float* __restrict__ gsq)
{
    __shared__ __bf16 xs[100 * 64];      // [halo px 10x10][64 ic], swizzled

    int b = blockIdx.x;
    int n = b / 49, t = b % 49;
    int h0 = (t / 7) * 8, w0 = (t % 7) * 8;
    int tid  = threadIdx.x;
    int lane = tid & 63, wid = tid >> 6;
    int l15 = lane & 15, l4 = lane >> 4;
    int oc0 = wid * 32;

    // ---- stage x halo: thread = (chunk c, px); 8 strided global loads,
    // one 16B LDS write at swizzled chunk (c ^ (px&7)) ----
    const float* xn = x + n * CIN * HH * WW;
    for (int u = tid; u < 800; u += 256) {
        int c = u / 100, px = u - c * 100;
        int r = px / 10, cc = px - r * 10;
        int gh = h0 - 1 + r, gw = w0 - 1 + cc;
        bool ok = ((unsigned)gh < 56u) & ((unsigned)gw < 56u);
        const float* src = xn + (c * 8) * (HH * WW) + gh * WW + gw;
        bf16x8 hv;
        #pragma unroll
        for (int j = 0; j < 8; ++j) {
            float v = ok ? src[j * HH * WW] : 0.0f;
            hv[j] = (__bf16)v;
        }
        *(bf16x8*)&xs[px * 64 + ((c ^ (px & 7)) * 8)] = hv;
    }
    __syncthreads();

    f32x4 acc[4][2] = {};

    int rb0  = (l15 >> 3) * 10 + (l15 & 7);      // halo row*10+col base
    int woff = (oc0 + l15) * 32 + l4 * 8;        // B fragment offset

    #pragma unroll 2
    for (int th = 0; th < 18; ++th) {
        int tap = th >> 1, half = th & 1;
        int kh = (tap * 11) >> 5;                // tap/3 for tap<9
        int toff = kh * 10 + (tap - kh * 3);     // kh*10+kw
        const __bf16* bp = whi + th * 4096;
        bf16x8 b0 = *(const bf16x8*)&bp[woff];
        bf16x8 b1 = *(const bf16x8*)&bp[woff + 512];
        int c0 = half * 4 + l4;
        #pragma unroll
        for (int mt = 0; mt < 4; ++mt) {
            int R  = rb0 + mt * 20 + toff;
            int ae = R * 64 + ((c0 ^ (R & 7)) * 8);
            bf16x8 ah = *(const bf16x8*)&xs[ae];
            acc[mt][0] = __builtin_amdgcn_mfma_f32_16x16x32_bf16(ah, b0, acc[mt][0], 0, 0, 0);
            acc[mt][1] = __builtin_amdgcn_mfma_f32_16x16x32_bf16(ah, b1, acc[mt][1], 0, 0, 0);
        }
    }

    // ---- write raw y (pre-BN): float4 per (mt,nt) ----
    // C/D layout: col(oc_local)=lane&15, row(M-local)=(lane>>4)*4 + reg  [m89]
    float* yn = y + n * COUT * HH * WW;
    int pyb = l4 >> 1;
    int gwo = w0 + (l4 & 1) * 4;
    #pragma unroll
    for (int mt = 0; mt < 4; ++mt) {
        int gh = h0 + mt * 2 + pyb;
        #pragma unroll
        for (int nt = 0; nt < 2; ++nt) {
            int oc = oc0 + nt * 16 + l15;
            *(float4*)&yn[(oc * HH + gh) * WW + gwo] = *(float4*)&acc[mt][nt];
        }
    }

    // ---- per-channel partial stats; red aliases xs (all xs reads done) ----
    float* red = (float*)xs;
    __syncthreads();
    #pragma unroll
    for (int nt = 0; nt < 2; ++nt) {
        float s = 0.0f, sq = 0.0f;
        #pragma unroll
        for (int mt = 0; mt < 4; ++mt)
            #pragma unroll
            for (int r = 0; r < 4; ++r) {
                float v = acc[mt][nt][r];
                s += v; sq += v * v;
            }
        s  += __shfl_xor(s, 16, 64);  s  += __shfl_xor(s, 32, 64);
        sq += __shfl_xor(sq, 16, 64); sq += __shfl_xor(sq, 32, 64);
        if (l4 == 0) {
            int oc = oc0 + nt * 16 + l15;
            red[oc] = s; red[128 + oc] = sq;
        }
    }
    __syncthreads();
    if (tid < 128) {
        atomicAdd(&gsum[tid], red[tid]);
        atomicAdd(&gsq[tid],  red[128 + tid]);
    }
}

// ---------------- BN scale/shift from accumulated stats ----------------------
__global__ void bn_finalize(const float* __restrict__ gsum, const float* __restrict__ gsq,
                            const float* __restrict__ gamma, const float* __restrict__ beta,
                            float* __restrict__ scale, float* __restrict__ shift)
{
    int c = threadIdx.x;
    float mean = gsum[c] * (1.0f / NPIX);
    float var  = gsq[c]  * (1.0f / NPIX) - mean * mean;
    float inv  = gamma[c] / sqrtf(var + BN_EPSF);
    scale[c] = inv;
    shift[c] = beta[c] - mean * inv;
}

// ---------------- apply BN + clip, in-place on d_out, float4 -----------------
__global__ __launch_bounds__(256) void bn_apply(float* __restrict__ y,
        const float* __restrict__ scale, const float* __restrict__ shift)
{
    const int total4 = NB * COUT * HH * WW / 4;   // 3211264
    int idx = blockIdx.x * blockDim.x + threadIdx.x;
    int stride = gridDim.x * blockDim.x;
    for (int i4 = idx; i4 < total4; i4 += stride) {
        int c = (i4 / 784) & 127;
        float sc = scale[c], sh = shift[c];
        float4 v = ((float4*)y)[i4];
        v.x = fminf(fmaxf(fmaf(v.x, sc, sh), 0.0f), 6.0f);
        v.y = fminf(fmaxf(fmaf(v.y, sc, sh), 0.0f), 6.0f);
        v.z = fminf(fmaxf(fmaf(v.z, sc, sh), 0.0f), 6.0f);
        v.w = fminf(fmaxf(fmaf(v.w, sc, sh), 0.0f), 6.0f);
        ((float4*)y)[i4] = v;
    }
}

extern "C" void kernel_launch(void* const* d_in, const int* in_sizes, int n_in,
                              void* d_out, int out_size, void* d_ws, size_t ws_size,
                              hipStream_t stream) {
    const float* x     = (const float*)d_in[0];
    const float* wb    = (const float*)d_in[1];
    const float* gamma = (const float*)d_in[2];
    const float* beta  = (const float*)d_in[3];
    float* y = (float*)d_out;

    __bf16* whi = (__bf16*)d_ws;                 // 73728 bf16
    float* gsum  = (float*)(whi + 73728);
    float* gsq   = gsum + 128;
    float* scale = gsq + 128;
    float* shift = scale + 128;

    zero_sums<<<1, 256, 0, stream>>>(gsum);
    assemble_w<<<(576 * 128 + 255) / 256, 256, 0, stream>>>(wb, whi);
    conv_mfma<<<NB * 49, 256, 0, stream>>>(x, whi, y, gsum, gsq);
    bn_finalize<<<1, COUT, 0, stream>>>(gsum, gsq, gamma, beta, scale, shift);
    bn_apply<<<2048, 256, 0, stream>>>(y, scale, shift);
}